// Round 6
// baseline (85.226 us; speedup 1.0000x reference)
//
#include <hip/hip_runtime.h>
#include <math.h>

// S4D kernel: K[h,l] = 2 * Re( sum_n C_n * exp(dtA_n * l) ), H=512, NH=32, L=8192.
// Factorization: l = 64*l1 + l0, exp(dtA*l) = exp(dtA*64*l1) * exp(dtA*l0).
// One block per h, 128 threads. LDS tables: D[n][l1] = 2*Ccoef_n*exp(dtA_n*64*l1)
// (32x128 cplx), E0[n][l0] = exp(dtA_n*l0) (32x64 cplx). K = Re(D*E0) per element.
// v3: 8x8 per-thread tile (1.0 B/FMA LDS traffic, vs 1.5 for 4x8) + fully-SSA
// inner loop (no address-of locals -> no scratch). 2.0 folded into D.

constexpr int H_DIM = 512;
constexpr int NH    = 32;
constexpr int LLEN  = 8192;
constexpr int L0N   = 64;    // inner factor
constexpr int L1N   = 128;   // outer factor: LLEN = L0N * L1N
constexpr int TPB   = 128;   // threads per block

constexpr double INV_2PI = 0.15915494309189535;

typedef float f32x4 __attribute__((ext_vector_type(4)));

__global__ __launch_bounds__(TPB) void s4d_kernel(
    const float* __restrict__ C_real,
    const float* __restrict__ C_imag,
    const float* __restrict__ log_dt,
    const float* __restrict__ log_a_real,
    const float* __restrict__ A_imag,
    float* __restrict__ K)
{
    __shared__ float E0r[NH][L0N];
    __shared__ float E0i[NH][L0N];
    __shared__ float Dr[NH][L1N];
    __shared__ float Di[NH][L1N];
    __shared__ float  s_a[NH];      // dtA real part (decay rate)
    __shared__ float  s_cr[NH];     // C coefficient real (x2 folded in)
    __shared__ float  s_ci[NH];     // C coefficient imag (x2 folded in)
    __shared__ double s_rev[NH];    // dtA imag / (2*pi): revolutions per unit t

    const int h   = blockIdx.x;
    const int tid = threadIdx.x;

    // ---- Phase 1: per-n scalars (first 32 threads) ----
    if (tid < NH) {
        const int n = tid;
        const float dt   = expf(log_dt[h]);
        const float a_re = -expf(log_a_real[h * NH + n]);  // A real
        const float a_im = A_imag[h * NH + n];             // A imag
        const float da_re = a_re * dt;                     // dtA real
        const float da_im = a_im * dt;                     // dtA imag
        // C = (Cr + i*Ci) * (exp(dtA) - 1) / A
        const float er = expf(da_re);
        float sn, cs;
        sincosf(da_im, &sn, &cs);  // |da_im| <= ~10 rad, accurate libm version
        const float num_re = er * cs - 1.0f;
        const float num_im = er * sn;
        const float inv    = 1.0f / (a_re * a_re + a_im * a_im);
        const float q_re = (num_re * a_re + num_im * a_im) * inv;
        const float q_im = (num_im * a_re - num_re * a_im) * inv;
        const float cr = C_real[h * NH + n];
        const float ci = C_imag[h * NH + n];
        // Fold the final "2 * Re(...)" factor into the C coefficient here.
        s_cr[n]  = 2.0f * (cr * q_re - ci * q_im);
        s_ci[n]  = 2.0f * (cr * q_im + ci * q_re);
        s_a[n]   = da_re;
        s_rev[n] = (double)da_im * INV_2PI;
    }
    __syncthreads();

    // ---- Phase 2a: E0 table (32*64 = 2048 entries) ----
    for (int e = tid; e < NH * L0N; e += TPB) {
        const int n = e >> 6;
        const int t = e & 63;
        const double rev = s_rev[n] * (double)t;
        const float  fr  = (float)(rev - floor(rev));   // [0,1) revolutions
        const float  mag = expf(s_a[n] * (float)t);
        E0r[n][t] = mag * __builtin_amdgcn_cosf(fr);    // v_cos_f32: input in revolutions
        E0i[n][t] = mag * __builtin_amdgcn_sinf(fr);
    }

    // ---- Phase 2b: D table (32*128 = 4096 entries), folds in C coefficient ----
    for (int e = tid; e < NH * L1N; e += TPB) {
        const int n  = e >> 7;
        const int l1 = e & 127;
        const int t  = l1 << 6;  // 64*l1
        const double rev = s_rev[n] * (double)t;
        const float  fr  = (float)(rev - floor(rev));
        const float  mag = expf(s_a[n] * (float)t);
        const float  wr  = mag * __builtin_amdgcn_cosf(fr);
        const float  wi  = mag * __builtin_amdgcn_sinf(fr);
        Dr[n][l1] = s_cr[n] * wr - s_ci[n] * wi;
        Di[n][l1] = s_cr[n] * wi + s_ci[n] * wr;
    }
    __syncthreads();

    // ---- Phase 3: main compute. Thread tile = 8 (l1) x 8 (l0). ----
    const int g1  = tid >> 3;    // 0..15
    const int g0  = tid & 7;     // 0..7
    const int l1b = g1 * 8;
    const int l0b = g0 * 8;

    // Accumulators: all indices compile-time after unroll -> pure VGPRs.
    float acc[8][8];
#pragma unroll
    for (int i = 0; i < 8; ++i)
#pragma unroll
        for (int j = 0; j < 8; ++j) acc[i][j] = 0.0f;

#pragma unroll 4
    for (int n = 0; n < NH; ++n) {
        // 8 x ds_read_b128. No address-of on any local -> no scratch.
        const f32x4 dr0 = *reinterpret_cast<const f32x4*>(&Dr[n][l1b]);
        const f32x4 dr1 = *reinterpret_cast<const f32x4*>(&Dr[n][l1b + 4]);
        const f32x4 di0 = *reinterpret_cast<const f32x4*>(&Di[n][l1b]);
        const f32x4 di1 = *reinterpret_cast<const f32x4*>(&Di[n][l1b + 4]);
        const f32x4 er0 = *reinterpret_cast<const f32x4*>(&E0r[n][l0b]);
        const f32x4 er1 = *reinterpret_cast<const f32x4*>(&E0r[n][l0b + 4]);
        const f32x4 ei0 = *reinterpret_cast<const f32x4*>(&E0i[n][l0b]);
        const f32x4 ei1 = *reinterpret_cast<const f32x4*>(&E0i[n][l0b + 4]);
#pragma unroll
        for (int i = 0; i < 4; ++i) {
            const float dra = dr0[i];
            const float dia = di0[i];
            const float drb = dr1[i];
            const float dib = di1[i];
#pragma unroll
            for (int j = 0; j < 4; ++j) {
                acc[i][j]         = fmaf(dra,  er0[j], acc[i][j]);
                acc[i][j]         = fmaf(-dia, ei0[j], acc[i][j]);
                acc[i][j + 4]     = fmaf(dra,  er1[j], acc[i][j + 4]);
                acc[i][j + 4]     = fmaf(-dia, ei1[j], acc[i][j + 4]);
                acc[i + 4][j]     = fmaf(drb,  er0[j], acc[i + 4][j]);
                acc[i + 4][j]     = fmaf(-dib, ei0[j], acc[i + 4][j]);
                acc[i + 4][j + 4] = fmaf(drb,  er1[j], acc[i + 4][j + 4]);
                acc[i + 4][j + 4] = fmaf(-dib, ei1[j], acc[i + 4][j + 4]);
            }
        }
    }

    // ---- Store: 8 rows x 8 contiguous floats (two float4 per row) ----
    // 2.0 factor already folded into D via s_cr/s_ci.
    float* base = K + (size_t)h * LLEN + l1b * L0N + l0b;
#pragma unroll
    for (int i = 0; i < 8; ++i) {
        f32x4 o0, o1;
        o0[0] = acc[i][0]; o0[1] = acc[i][1]; o0[2] = acc[i][2]; o0[3] = acc[i][3];
        o1[0] = acc[i][4]; o1[1] = acc[i][5]; o1[2] = acc[i][6]; o1[3] = acc[i][7];
        float* dst = base + i * L0N;
        reinterpret_cast<f32x4*>(dst)[0] = o0;
        reinterpret_cast<f32x4*>(dst)[1] = o1;
    }
}

extern "C" void kernel_launch(void* const* d_in, const int* in_sizes, int n_in,
                              void* d_out, int out_size, void* d_ws, size_t ws_size,
                              hipStream_t stream) {
    const float* C_real     = (const float*)d_in[0];
    const float* C_imag     = (const float*)d_in[1];
    const float* log_dt     = (const float*)d_in[2];
    const float* log_a_real = (const float*)d_in[3];
    const float* A_imag     = (const float*)d_in[4];
    float* K = (float*)d_out;
    hipLaunchKernelGGL(s4d_kernel, dim3(H_DIM), dim3(TPB), 0, stream,
                       C_real, C_imag, log_dt, log_a_real, A_imag, K);
}